// Round 2
// baseline (297.846 us; speedup 1.0000x reference)
//
#include <hip/hip_runtime.h>
#include <stdint.h>

// SpectralFreqTimeConv2D: B=32, N=128, C=32 (cin=cout), M=17 kept modes/axis,
// TDIM=256. Only rows {0..16, 111..127} x cols {0..16} of the rFFT2 are used,
// so we evaluate truncated DFTs directly (4 small GEMM-shaped stages).
// All inputs/outputs are fp32 per the reference; all math in fp32.

#define TWO_PI_OVER_128 0.04908738521234052f

// ---------------- K0: t1/t2 = t_emb @ (k_real, k_imag) -> tbuf[which][b][i][2]
__global__ __launch_bounds__(128) void k_tproj(
    const float* __restrict__ temb, const float* __restrict__ k1r, const float* __restrict__ k1i,
    const float* __restrict__ k2r, const float* __restrict__ k2i, float* __restrict__ tbuf)
{
    int b = blockIdx.x, tid = threadIdx.x;
    __shared__ float ts[256];
    for (int d = tid; d < 256; d += 128) ts[d] = temb[b * 256 + d];
    __syncthreads();
    if (tid < 68) {
        int which = (tid >= 34) ? 1 : 0;
        int rem = tid - which * 34;
        int i = rem >> 1, part = rem & 1;
        const float* kp = which ? (part ? k2i : k2r) : (part ? k1i : k1r);
        float acc = 0.f;
        for (int d = 0; d < 256; ++d) acc += ts[d] * kp[d * 17 + i];
        tbuf[((which * 32 + b) * 17 + i) * 2 + part] = acc;
    }
}

// ---------------- K1: y-axis DFT. block = (b,x). T1[b][j][x][c] complex.
__global__ __launch_bounds__(256) void k_fwd_y(const float* __restrict__ x, float2* __restrict__ T1)
{
    int blk = blockIdx.x;
    int b = blk >> 7, xr = blk & 127;
    __shared__ float xs[128 * 32];
    int tid = threadIdx.x;
    const float4* xv = (const float4*)(x + ((size_t)blk << 12));
    float4* xs4 = (float4*)xs;
    for (int i = tid; i < 1024; i += 256) xs4[i] = xv[i];
    __syncthreads();
    int c = tid & 31, g = tid >> 5;       // g in 0..7; thread owns j in {g, g+8, 16(g==0)}
    int jl[3] = {g, g + 8, 16};
    float stc[3], sts[3];
#pragma unroll
    for (int t = 0; t < 3; ++t) {
        float a = -TWO_PI_OVER_128 * (float)jl[t];
        sincosf(a, &sts[t], &stc[t]);     // step = e^{-2pi i j/128}
    }
    float cr[3] = {1.f, 1.f, 1.f}, ci[3] = {0.f, 0.f, 0.f};
    float re[3] = {0.f, 0.f, 0.f}, im[3] = {0.f, 0.f, 0.f};
    const float* xc = xs + c;
#pragma unroll 4
    for (int y = 0; y < 128; ++y) {
        float v = xc[y << 5];
#pragma unroll
        for (int t = 0; t < 3; ++t) {
            re[t] = fmaf(v, cr[t], re[t]);
            im[t] = fmaf(v, ci[t], im[t]);
            float nr = cr[t] * stc[t] - ci[t] * sts[t];
            ci[t] = fmaf(cr[t], sts[t], ci[t] * stc[t]);
            cr[t] = nr;
        }
    }
    const float s = 1.f / 16384.f;        // norm='forward'
    int nj = (g == 0) ? 3 : 2;
    for (int t = 0; t < nj; ++t) {
        int j = jl[t];
        size_t off = ((size_t)((b * 17 + j) * 128 + xr) << 5) + c;
        T1[off] = make_float2(re[t] * s, im[t] * s);
    }
}

// ---------------- K2: x-axis DFT (34 rows) + channel mix + t-scale. block = (b,j).
// Y[b][j][ii][o] complex, ii 0..33 (0..16 -> rows 0..16 w/ w1,t1; 17..33 -> rows 111..127 w/ w2,t2)
__global__ __launch_bounds__(256) void k_fwd_x_mix(
    const float2* __restrict__ T1, const float* __restrict__ w1r, const float* __restrict__ w1i,
    const float* __restrict__ w2r, const float* __restrict__ w2i,
    const float* __restrict__ tbuf, float2* __restrict__ Y)
{
    int blk = blockIdx.x;
    int b = blk / 17, j = blk - b * 17;
    __shared__ float4 Ts4[2048];          // T1[b][j][x][c] as float4 = 2 complex
    __shared__ float2 Xf[34 * 32];
    int tid = threadIdx.x;
    const float4* s4 = (const float4*)(T1 + (size_t)blk * 4096);
    for (int i = tid; i < 2048; i += 256) Ts4[i] = s4[i];
    __syncthreads();
    // stage A: Xf[ii][c] = sum_x T[x][c] * e^{-2pi i f(ii) x/128}
    {
        int cp = tid & 15, g = tid >> 4;  // c-pair, g in 0..15; ii in {g, g+16, g+32(g<2)}
        int il[3] = {g, g + 16, g + 32};
        float stc[3], sts[3];
#pragma unroll
        for (int t = 0; t < 3; ++t) {
            int i = il[t];
            int f = (i < 17) ? i : i + 94;
            float a = -TWO_PI_OVER_128 * (float)(f & 127);
            sincosf(a, &sts[t], &stc[t]);
        }
        float cr[3] = {1.f, 1.f, 1.f}, ci[3] = {0.f, 0.f, 0.f};
        float r0[3] = {0,0,0}, i0[3] = {0,0,0}, r1[3] = {0,0,0}, i1[3] = {0,0,0};
        const float4* Tc = Ts4 + cp;
#pragma unroll 2
        for (int xx = 0; xx < 128; ++xx) {
            float4 tv = Tc[xx << 4];      // (re_c0, im_c0, re_c1, im_c1)
#pragma unroll
            for (int t = 0; t < 3; ++t) {
                r0[t] += tv.x * cr[t] - tv.y * ci[t];
                i0[t] += tv.x * ci[t] + tv.y * cr[t];
                r1[t] += tv.z * cr[t] - tv.w * ci[t];
                i1[t] += tv.z * ci[t] + tv.w * cr[t];
                float nr = cr[t] * stc[t] - ci[t] * sts[t];
                ci[t] = fmaf(cr[t], sts[t], ci[t] * stc[t]);
                cr[t] = nr;
            }
        }
#pragma unroll
        for (int t = 0; t < 3; ++t) {
            int i = il[t];
            if (i < 34) {
                Xf[i * 32 + cp * 2]     = make_float2(r0[t], i0[t]);
                Xf[i * 32 + cp * 2 + 1] = make_float2(r1[t], i1[t]);
            }
        }
    }
    __syncthreads();
    // stage B: Y[ii][o] = t[ii] * sum_c Xf[ii][c] * w[irow,j,c,o]
    {
        int o = tid & 31, gi = tid >> 5;
#pragma unroll
        for (int t = 0; t < 5; ++t) {
            int ii = gi + (t << 3);
            if (ii < 34) {
                int irow = (ii < 17) ? ii : ii - 17;
                const float* wr = ((ii < 17) ? w1r : w2r) + ((irow * 17 + j) << 10) + o;
                const float* wi = ((ii < 17) ? w1i : w2i) + ((irow * 17 + j) << 10) + o;
                float ar = 0.f, ai = 0.f;
#pragma unroll 8
                for (int cc2 = 0; cc2 < 32; ++cc2) {
                    float2 xv = Xf[ii * 32 + cc2];
                    float wre = wr[cc2 << 5];
                    float wim = wi[cc2 << 5];
                    ar += xv.x * wre - xv.y * wim;
                    ai += xv.x * wim + xv.y * wre;
                }
                int which = (ii >= 17) ? 1 : 0;
                const float* tp = tbuf + ((which * 32 + b) * 17 + irow) * 2;
                float tr = tp[0], ti = tp[1];
                Y[(size_t)blk * (34 * 32) + ii * 32 + o] =
                    make_float2(ar * tr - ai * ti, ar * ti + ai * tr);
            }
        }
    }
}

// ---------------- K3: inverse x-axis (full complex ifft, 34 nonzero rows). block = (b,j).
// U[b][x][j][o] complex = sum_ii Y[ii][o] * e^{+2pi i f(ii) x/128}
__global__ __launch_bounds__(256) void k_inv_x(const float2* __restrict__ Y, float2* __restrict__ U)
{
    int blk = blockIdx.x;
    int b = blk / 17, j = blk - b * 17;
    __shared__ float2 Ys[34 * 32];
    __shared__ float ct[128], st[128];
    int tid = threadIdx.x;
    if (tid < 128) {
        float a = TWO_PI_OVER_128 * (float)tid;
        sincosf(a, &st[tid], &ct[tid]);
    }
    const float2* src = Y + (size_t)blk * (34 * 32);
    for (int i = tid; i < 34 * 32; i += 256) Ys[i] = src[i];
    __syncthreads();
    int o = tid & 31, g = tid >> 5;
    float yr[34], yi[34];
#pragma unroll
    for (int i = 0; i < 34; ++i) { float2 v = Ys[i * 32 + o]; yr[i] = v.x; yi[i] = v.y; }
    for (int xi = 0; xi < 16; ++xi) {
        int xr = (xi << 3) + g;
        float cx = ct[xr], sx = st[xr];           // step e^{+2pi i x/128}
        float cr = 1.f, ci = 0.f, re = 0.f, im = 0.f;
#pragma unroll
        for (int i = 0; i < 17; ++i) {            // rows 0..16
            re += yr[i] * cr - yi[i] * ci;
            im += yr[i] * ci + yi[i] * cr;
            float nr = cr * cx - ci * sx;
            ci = fmaf(cr, sx, ci * cx);
            cr = nr;
        }
        int k2 = (111 * xr) & 127;                // rows 111..127
        cr = ct[k2]; ci = st[k2];
#pragma unroll
        for (int i = 17; i < 34; ++i) {
            re += yr[i] * cr - yi[i] * ci;
            im += yr[i] * ci + yi[i] * cr;
            float nr = cr * cx - ci * sx;
            ci = fmaf(cr, sx, ci * cx);
            cr = nr;
        }
        U[(((size_t)(b * 128 + xr)) * 17 + j) * 32 + o] = make_float2(re, im);
    }
}

// ---------------- K4: inverse y-axis c2r (17 nonzero bins; Im of bin0 ignored). block = (b,x).
__global__ __launch_bounds__(256) void k_inv_y(const float2* __restrict__ U, float* __restrict__ out)
{
    int blk = blockIdx.x;
    __shared__ float2 Us[17 * 32];
    __shared__ float ct[128], st[128];
    int tid = threadIdx.x;
    if (tid < 128) {
        float a = TWO_PI_OVER_128 * (float)tid;
        sincosf(a, &st[tid], &ct[tid]);
    }
    const float2* src = U + (size_t)blk * (17 * 32);
    for (int i = tid; i < 544; i += 256) Us[i] = src[i];
    __syncthreads();
    int oc = tid & 31, g = tid >> 5;
    float ur[17], ui[17];
#pragma unroll
    for (int jj = 0; jj < 17; ++jj) {
        float2 v = Us[jj * 32 + oc];
        float sc2 = (jj == 0) ? 1.f : 2.f;
        ur[jj] = v.x * sc2; ui[jj] = v.y * sc2;
    }
    float* op = out + ((size_t)blk << 12) + oc;
    for (int yi = 0; yi < 16; ++yi) {
        int y = (yi << 3) + g;
        float cy = ct[y], sy = st[y];
        float cr = cy, ci = sy;                   // j=1 rotator
        float acc = ur[0];                        // DC: real part only (c2r semantics)
#pragma unroll
        for (int jj = 1; jj < 17; ++jj) {
            acc += ur[jj] * cr - ui[jj] * ci;
            float nr = cr * cy - ci * sy;
            ci = fmaf(cr, sy, ci * cy);
            cr = nr;
        }
        op[y << 5] = acc;
    }
}

extern "C" void kernel_launch(void* const* d_in, const int* in_sizes, int n_in,
                              void* d_out, int out_size, void* d_ws, size_t ws_size,
                              hipStream_t stream)
{
    const float* x    = (const float*)d_in[0];
    const float* temb = (const float*)d_in[1];
    const float* w1r  = (const float*)d_in[2];
    const float* w1i  = (const float*)d_in[3];
    const float* w2r  = (const float*)d_in[4];
    const float* w2i  = (const float*)d_in[5];
    const float* k1r  = (const float*)d_in[6];
    const float* k1i  = (const float*)d_in[7];
    const float* k2r  = (const float*)d_in[8];
    const float* k2i  = (const float*)d_in[9];
    float* out = (float*)d_out;

    // Workspace: T1 (17.8 MB, reused as U) | Y (4.7 MB) | tbuf (8.5 KB) = 22.6 MB
    char* ws = (char*)d_ws;
    float2* T1 = (float2*)ws;                              // 32*17*128*32 float2
    float2* Yb = (float2*)(ws + 17825792);                 // 32*17*34*32 float2
    float*  tb = (float*)(ws + 17825792 + 4734976);        // 2*32*17*2 floats
    float2* U  = T1;                                       // T1 dead after K2

    k_tproj    <<<32,   128, 0, stream>>>(temb, k1r, k1i, k2r, k2i, tb);
    k_fwd_y    <<<4096, 256, 0, stream>>>(x, T1);
    k_fwd_x_mix<<<544,  256, 0, stream>>>(T1, w1r, w1i, w2r, w2i, tb, Yb);
    k_inv_x    <<<544,  256, 0, stream>>>(Yb, U);
    k_inv_y    <<<4096, 256, 0, stream>>>(U, out);
}

// Round 3
// 249.624 us; speedup vs baseline: 1.1932x; 1.1932x over previous
//
#include <hip/hip_runtime.h>
#include <stdint.h>

// SpectralFreqTimeConv2D: B=32, N=128, C=32, M=17 modes/axis, TDIM=256.
// Truncated-DFT factorization; R3: y-symmetry folding + channel-amortized
// rotators in K1/K4 (the two VALU-bound hot kernels per R2 rocprof).

#define TWO_PI_OVER_128 0.04908738521234052f

// ---------------- K0: t1/t2 = t_emb @ (k_real, k_imag) -> tbuf[which][b][i][2]
__global__ __launch_bounds__(128) void k_tproj(
    const float* __restrict__ temb, const float* __restrict__ k1r, const float* __restrict__ k1i,
    const float* __restrict__ k2r, const float* __restrict__ k2i, float* __restrict__ tbuf)
{
    int b = blockIdx.x, tid = threadIdx.x;
    __shared__ float ts[256];
    for (int d = tid; d < 256; d += 128) ts[d] = temb[b * 256 + d];
    __syncthreads();
    if (tid < 68) {
        int which = (tid >= 34) ? 1 : 0;
        int rem = tid - which * 34;
        int i = rem >> 1, part = rem & 1;
        const float* kp = which ? (part ? k2i : k2r) : (part ? k1i : k1r);
        float acc = 0.f;
        for (int d = 0; d < 256; ++d) acc += ts[d] * kp[d * 17 + i];
        tbuf[((which * 32 + b) * 17 + i) * 2 + part] = acc;
    }
}

// ---------------- K1: y-axis DFT with y<->128-y folding. block = (b,x), 64 thr.
// T1[b][j][x][c] complex. Re X_j = x0 + (-1)^j x64 + sum_{y=1..63} s_y cos(ang y)
// Im X_j = sum d_y sin(ang y), ang = -2pi j/128, s=x[y]+x[128-y], d=x[y]-x[128-y].
__global__ __launch_bounds__(64) void k_fwd_y(const float* __restrict__ x, float2* __restrict__ T1)
{
    int blk = blockIdx.x;
    int b = blk >> 7, xr = blk & 127;
    __shared__ float xs[128 * 32];
    int tid = threadIdx.x;
    const float4* xv = (const float4*)(x + ((size_t)blk << 12));
    float4* xs4 = (float4*)xs;
#pragma unroll
    for (int i = 0; i < 16; ++i) xs4[tid + (i << 6)] = xv[tid + (i << 6)];
    __syncthreads();
    // fold pass: each item (y,c), y=1..63 owned by exactly one thread
    for (int i = tid; i < 2016; i += 64) {
        int y = (i >> 5) + 1, c = i & 31;
        float a = xs[(y << 5) + c], q = xs[((128 - y) << 5) + c];
        xs[(y << 5) + c] = a + q;
        xs[((128 - y) << 5) + c] = a - q;
    }
    __syncthreads();
    int jg = tid >> 3, cg = tid & 7, c0 = cg << 2;
    float re[2][4] = {{0,0,0,0},{0,0,0,0}}, im[2][4] = {{0,0,0,0},{0,0,0,0}};
    float stc[2], sts[2], cr[2], ci[2];
#pragma unroll
    for (int t = 0; t < 2; ++t) {
        int j = jg + t * 8;
        float sn, cs; sincosf(TWO_PI_OVER_128 * (float)j, &sn, &cs);
        stc[t] = cs; sts[t] = -sn; cr[t] = cs; ci[t] = -sn;   // start at y=1
    }
    for (int y = 1; y <= 63; ++y) {
        float4 s = *(const float4*)&xs[(y << 5) + c0];
        float4 d = *(const float4*)&xs[((128 - y) << 5) + c0];
#pragma unroll
        for (int t = 0; t < 2; ++t) {
            re[t][0] = fmaf(s.x, cr[t], re[t][0]);
            re[t][1] = fmaf(s.y, cr[t], re[t][1]);
            re[t][2] = fmaf(s.z, cr[t], re[t][2]);
            re[t][3] = fmaf(s.w, cr[t], re[t][3]);
            im[t][0] = fmaf(d.x, ci[t], im[t][0]);
            im[t][1] = fmaf(d.y, ci[t], im[t][1]);
            im[t][2] = fmaf(d.z, ci[t], im[t][2]);
            im[t][3] = fmaf(d.w, ci[t], im[t][3]);
            float nr = cr[t] * stc[t] - ci[t] * sts[t];
            ci[t] = fmaf(cr[t], sts[t], ci[t] * stc[t]);
            cr[t] = nr;
        }
    }
    const float s_ = 1.f / 16384.f;   // norm='forward'
    float x0[4], x64[4];
    *(float4*)x0  = *(const float4*)&xs[c0];
    *(float4*)x64 = *(const float4*)&xs[(64 << 5) + c0];
#pragma unroll
    for (int t = 0; t < 2; ++t) {
        int j = jg + t * 8;
        float sg = (j & 1) ? -1.f : 1.f;
        float2* p = T1 + (((size_t)(b * 17 + j) * 128 + xr) << 5) + c0;
        float4 v0 = make_float4((re[t][0] + x0[0] + sg * x64[0]) * s_, im[t][0] * s_,
                                (re[t][1] + x0[1] + sg * x64[1]) * s_, im[t][1] * s_);
        float4 v1 = make_float4((re[t][2] + x0[2] + sg * x64[2]) * s_, im[t][2] * s_,
                                (re[t][3] + x0[3] + sg * x64[3]) * s_, im[t][3] * s_);
        ((float4*)p)[0] = v0; ((float4*)p)[1] = v1;
    }
    if (jg == 0) {   // j = 16, step e^{-i pi/4}
        float re2[4] = {0,0,0,0}, im2[4] = {0,0,0,0};
        const float cs = 0.7071067811865476f, sn = -0.7071067811865476f;
        float cr2 = cs, ci2 = sn;
        for (int y = 1; y <= 63; ++y) {
            float4 s = *(const float4*)&xs[(y << 5) + c0];
            float4 d = *(const float4*)&xs[((128 - y) << 5) + c0];
            re2[0] = fmaf(s.x, cr2, re2[0]); re2[1] = fmaf(s.y, cr2, re2[1]);
            re2[2] = fmaf(s.z, cr2, re2[2]); re2[3] = fmaf(s.w, cr2, re2[3]);
            im2[0] = fmaf(d.x, ci2, im2[0]); im2[1] = fmaf(d.y, ci2, im2[1]);
            im2[2] = fmaf(d.z, ci2, im2[2]); im2[3] = fmaf(d.w, ci2, im2[3]);
            float nr = cr2 * cs - ci2 * sn;
            ci2 = fmaf(cr2, sn, ci2 * cs);
            cr2 = nr;
        }
        float2* p = T1 + (((size_t)(b * 17 + 16) * 128 + xr) << 5) + c0;
        float4 v0 = make_float4((re2[0] + x0[0] + x64[0]) * s_, im2[0] * s_,
                                (re2[1] + x0[1] + x64[1]) * s_, im2[1] * s_);
        float4 v1 = make_float4((re2[2] + x0[2] + x64[2]) * s_, im2[2] * s_,
                                (re2[3] + x0[3] + x64[3]) * s_, im2[3] * s_);
        ((float4*)p)[0] = v0; ((float4*)p)[1] = v1;
    }
}

// ---------------- K2: x-axis DFT (34 rows) + channel mix + t-scale. block = (b,j).
__global__ __launch_bounds__(256) void k_fwd_x_mix(
    const float2* __restrict__ T1, const float* __restrict__ w1r, const float* __restrict__ w1i,
    const float* __restrict__ w2r, const float* __restrict__ w2i,
    const float* __restrict__ tbuf, float2* __restrict__ Y)
{
    int blk = blockIdx.x;
    int b = blk / 17, j = blk - b * 17;
    __shared__ float4 Ts4[2048];
    __shared__ float2 Xf[34 * 32];
    int tid = threadIdx.x;
    const float4* s4 = (const float4*)(T1 + (size_t)blk * 4096);
    for (int i = tid; i < 2048; i += 256) Ts4[i] = s4[i];
    __syncthreads();
    {
        int cp = tid & 15, g = tid >> 4;
        int il[3] = {g, g + 16, g + 32};
        float stc[3], sts[3];
#pragma unroll
        for (int t = 0; t < 3; ++t) {
            int i = il[t];
            int f = (i < 17) ? i : i + 94;
            float a = -TWO_PI_OVER_128 * (float)(f & 127);
            sincosf(a, &sts[t], &stc[t]);
        }
        float cr[3] = {1.f, 1.f, 1.f}, ci[3] = {0.f, 0.f, 0.f};
        float r0[3] = {0,0,0}, i0[3] = {0,0,0}, r1[3] = {0,0,0}, i1[3] = {0,0,0};
        const float4* Tc = Ts4 + cp;
#pragma unroll 2
        for (int xx = 0; xx < 128; ++xx) {
            float4 tv = Tc[xx << 4];
#pragma unroll
            for (int t = 0; t < 3; ++t) {
                r0[t] += tv.x * cr[t] - tv.y * ci[t];
                i0[t] += tv.x * ci[t] + tv.y * cr[t];
                r1[t] += tv.z * cr[t] - tv.w * ci[t];
                i1[t] += tv.z * ci[t] + tv.w * cr[t];
                float nr = cr[t] * stc[t] - ci[t] * sts[t];
                ci[t] = fmaf(cr[t], sts[t], ci[t] * stc[t]);
                cr[t] = nr;
            }
        }
#pragma unroll
        for (int t = 0; t < 3; ++t) {
            int i = il[t];
            if (i < 34) {
                Xf[i * 32 + cp * 2]     = make_float2(r0[t], i0[t]);
                Xf[i * 32 + cp * 2 + 1] = make_float2(r1[t], i1[t]);
            }
        }
    }
    __syncthreads();
    {
        int o = tid & 31, gi = tid >> 5;
#pragma unroll
        for (int t = 0; t < 5; ++t) {
            int ii = gi + (t << 3);
            if (ii < 34) {
                int irow = (ii < 17) ? ii : ii - 17;
                const float* wr = ((ii < 17) ? w1r : w2r) + ((irow * 17 + j) << 10) + o;
                const float* wi = ((ii < 17) ? w1i : w2i) + ((irow * 17 + j) << 10) + o;
                float ar = 0.f, ai = 0.f;
#pragma unroll 8
                for (int cc2 = 0; cc2 < 32; ++cc2) {
                    float2 xv = Xf[ii * 32 + cc2];
                    float wre = wr[cc2 << 5];
                    float wim = wi[cc2 << 5];
                    ar += xv.x * wre - xv.y * wim;
                    ai += xv.x * wim + xv.y * wre;
                }
                int which = (ii >= 17) ? 1 : 0;
                const float* tp = tbuf + ((which * 32 + b) * 17 + irow) * 2;
                float tr = tp[0], ti = tp[1];
                Y[(size_t)blk * (34 * 32) + ii * 32 + o] =
                    make_float2(ar * tr - ai * ti, ar * ti + ai * tr);
            }
        }
    }
}

// ---------------- K3: inverse x-axis. block = (b,j). U[b][x][j][o] complex.
__global__ __launch_bounds__(256) void k_inv_x(const float2* __restrict__ Y, float2* __restrict__ U)
{
    int blk = blockIdx.x;
    int b = blk / 17, j = blk - b * 17;
    __shared__ float2 Ys[34 * 32];
    __shared__ float ct[128], st[128];
    int tid = threadIdx.x;
    if (tid < 128) {
        float a = TWO_PI_OVER_128 * (float)tid;
        sincosf(a, &st[tid], &ct[tid]);
    }
    const float2* src = Y + (size_t)blk * (34 * 32);
    for (int i = tid; i < 34 * 32; i += 256) Ys[i] = src[i];
    __syncthreads();
    int o = tid & 31, g = tid >> 5;
    float yr[34], yi[34];
#pragma unroll
    for (int i = 0; i < 34; ++i) { float2 v = Ys[i * 32 + o]; yr[i] = v.x; yi[i] = v.y; }
    for (int xi = 0; xi < 16; ++xi) {
        int xr = (xi << 3) + g;
        float cx = ct[xr], sx = st[xr];
        float cr = 1.f, ci = 0.f, re = 0.f, im = 0.f;
#pragma unroll
        for (int i = 0; i < 17; ++i) {
            re += yr[i] * cr - yi[i] * ci;
            im += yr[i] * ci + yi[i] * cr;
            float nr = cr * cx - ci * sx;
            ci = fmaf(cr, sx, ci * cx);
            cr = nr;
        }
        int k2 = (111 * xr) & 127;
        cr = ct[k2]; ci = st[k2];
#pragma unroll
        for (int i = 17; i < 34; ++i) {
            re += yr[i] * cr - yi[i] * ci;
            im += yr[i] * ci + yi[i] * cr;
            float nr = cr * cx - ci * sx;
            ci = fmaf(cr, sx, ci * cx);
            cr = nr;
        }
        U[(((size_t)(b * 128 + xr)) * 17 + j) * 32 + o] = make_float2(re, im);
    }
}

// ---------------- K4: inverse y-axis c2r with y<->128-y pairing. block=(b,x), 128 thr.
// out[y] = base + A - B, out[128-y] = base + A + B; A = sum ur_j cos, B = sum ui_j sin.
__global__ __launch_bounds__(128) void k_inv_y(const float2* __restrict__ U, float* __restrict__ out)
{
    int blk = blockIdx.x;
    __shared__ float2 Us[17 * 32];
    int tid = threadIdx.x;
    const float4* src4 = (const float4*)(U + (size_t)blk * 544);
    float4* Us4 = (float4*)Us;
    for (int i = tid; i < 272; i += 128) Us4[i] = src4[i];
    __syncthreads();
    int cg = tid & 15, yg = tid >> 4, c0 = cg << 1;
    float base0, base1;
    {
        float4 v = *(const float4*)&Us[c0];   // j=0: real part only (c2r DC)
        base0 = v.x; base1 = v.z;
    }
    float urr[16][2], uii[16][2];
#pragma unroll
    for (int j = 1; j <= 16; ++j) {
        float4 v = *(const float4*)&Us[j * 32 + c0];
        urr[j-1][0] = 2.f * v.x; uii[j-1][0] = 2.f * v.y;
        urr[j-1][1] = 2.f * v.z; uii[j-1][1] = 2.f * v.w;
    }
    float* op = out + ((size_t)blk << 12);
    for (int k = 0; k < 9; ++k) {
        int y = yg + (k << 3);
        if (y > 64) break;
        float cy, sy; sincosf(TWO_PI_OVER_128 * (float)y, &sy, &cy);
        float cr = cy, ci = sy;
        float A0 = 0.f, A1 = 0.f, B0 = 0.f, B1 = 0.f;
#pragma unroll
        for (int j = 0; j < 16; ++j) {
            A0 = fmaf(urr[j][0], cr, A0);
            B0 = fmaf(uii[j][0], ci, B0);
            A1 = fmaf(urr[j][1], cr, A1);
            B1 = fmaf(uii[j][1], ci, B1);
            float nr = cr * cy - ci * sy;
            ci = fmaf(cr, sy, ci * cy);
            cr = nr;
        }
        *(float2*)&op[(y << 5) + c0] = make_float2(base0 + A0 - B0, base1 + A1 - B1);
        if (y > 0 && y < 64)
            *(float2*)&op[((128 - y) << 5) + c0] = make_float2(base0 + A0 + B0, base1 + A1 + B1);
    }
}

extern "C" void kernel_launch(void* const* d_in, const int* in_sizes, int n_in,
                              void* d_out, int out_size, void* d_ws, size_t ws_size,
                              hipStream_t stream)
{
    const float* x    = (const float*)d_in[0];
    const float* temb = (const float*)d_in[1];
    const float* w1r  = (const float*)d_in[2];
    const float* w1i  = (const float*)d_in[3];
    const float* w2r  = (const float*)d_in[4];
    const float* w2i  = (const float*)d_in[5];
    const float* k1r  = (const float*)d_in[6];
    const float* k1i  = (const float*)d_in[7];
    const float* k2r  = (const float*)d_in[8];
    const float* k2i  = (const float*)d_in[9];
    float* out = (float*)d_out;

    char* ws = (char*)d_ws;
    float2* T1 = (float2*)ws;                              // 32*17*128*32 float2
    float2* Yb = (float2*)(ws + 17825792);                 // 32*17*34*32 float2
    float*  tb = (float*)(ws + 17825792 + 4734976);        // 2*32*17*2 floats
    float2* U  = T1;                                       // T1 dead after K2

    k_tproj    <<<32,   128, 0, stream>>>(temb, k1r, k1i, k2r, k2i, tb);
    k_fwd_y    <<<4096, 64,  0, stream>>>(x, T1);
    k_fwd_x_mix<<<544,  256, 0, stream>>>(T1, w1r, w1i, w2r, w2i, tb, Yb);
    k_inv_x    <<<544,  256, 0, stream>>>(Yb, U);
    k_inv_y    <<<4096, 128, 0, stream>>>(U, out);
}

// Round 4
// 213.028 us; speedup vs baseline: 1.3982x; 1.1718x over previous
//
#include <hip/hip_runtime.h>
#include <stdint.h>

// SpectralFreqTimeConv2D: B=32, N=128, C=32, M=17. Truncated-DFT factorization.
// R4: fused x-DFT + channel-mix + inverse-x kernel (block=(b,j)) with
// conjugate-pair row folding (stage A) and output-pair folding (stage C).

#define TWO_PI_OVER_128 0.04908738521234052f

// ---------------- K0: t1/t2 = t_emb @ (k_real, k_imag) -> tbuf[which][b][i][2]
__global__ __launch_bounds__(128) void k_tproj(
    const float* __restrict__ temb, const float* __restrict__ k1r, const float* __restrict__ k1i,
    const float* __restrict__ k2r, const float* __restrict__ k2i, float* __restrict__ tbuf)
{
    int b = blockIdx.x, tid = threadIdx.x;
    __shared__ float ts[256];
    for (int d = tid; d < 256; d += 128) ts[d] = temb[b * 256 + d];
    __syncthreads();
    if (tid < 68) {
        int which = (tid >= 34) ? 1 : 0;
        int rem = tid - which * 34;
        int i = rem >> 1, part = rem & 1;
        const float* kp = which ? (part ? k2i : k2r) : (part ? k1i : k1r);
        float acc = 0.f;
        for (int d = 0; d < 256; ++d) acc += ts[d] * kp[d * 17 + i];
        tbuf[((which * 32 + b) * 17 + i) * 2 + part] = acc;
    }
}

// ---------------- K1: y-axis DFT with y<->128-y folding. block = (b,x), 64 thr.
__global__ __launch_bounds__(64) void k_fwd_y(const float* __restrict__ x, float2* __restrict__ T1)
{
    int blk = blockIdx.x;
    int b = blk >> 7, xr = blk & 127;
    __shared__ float xs[128 * 32];
    int tid = threadIdx.x;
    const float4* xv = (const float4*)(x + ((size_t)blk << 12));
    float4* xs4 = (float4*)xs;
#pragma unroll
    for (int i = 0; i < 16; ++i) xs4[tid + (i << 6)] = xv[tid + (i << 6)];
    __syncthreads();
    for (int i = tid; i < 2016; i += 64) {
        int y = (i >> 5) + 1, c = i & 31;
        float a = xs[(y << 5) + c], q = xs[((128 - y) << 5) + c];
        xs[(y << 5) + c] = a + q;
        xs[((128 - y) << 5) + c] = a - q;
    }
    __syncthreads();
    int jg = tid >> 3, cg = tid & 7, c0 = cg << 2;
    float re[2][4] = {{0,0,0,0},{0,0,0,0}}, im[2][4] = {{0,0,0,0},{0,0,0,0}};
    float stc[2], sts[2], cr[2], ci[2];
#pragma unroll
    for (int t = 0; t < 2; ++t) {
        int j = jg + t * 8;
        float sn, cs; sincosf(TWO_PI_OVER_128 * (float)j, &sn, &cs);
        stc[t] = cs; sts[t] = -sn; cr[t] = cs; ci[t] = -sn;
    }
    for (int y = 1; y <= 63; ++y) {
        float4 s = *(const float4*)&xs[(y << 5) + c0];
        float4 d = *(const float4*)&xs[((128 - y) << 5) + c0];
#pragma unroll
        for (int t = 0; t < 2; ++t) {
            re[t][0] = fmaf(s.x, cr[t], re[t][0]);
            re[t][1] = fmaf(s.y, cr[t], re[t][1]);
            re[t][2] = fmaf(s.z, cr[t], re[t][2]);
            re[t][3] = fmaf(s.w, cr[t], re[t][3]);
            im[t][0] = fmaf(d.x, ci[t], im[t][0]);
            im[t][1] = fmaf(d.y, ci[t], im[t][1]);
            im[t][2] = fmaf(d.z, ci[t], im[t][2]);
            im[t][3] = fmaf(d.w, ci[t], im[t][3]);
            float nr = cr[t] * stc[t] - ci[t] * sts[t];
            ci[t] = fmaf(cr[t], sts[t], ci[t] * stc[t]);
            cr[t] = nr;
        }
    }
    const float s_ = 1.f / 16384.f;
    float x0[4], x64[4];
    *(float4*)x0  = *(const float4*)&xs[c0];
    *(float4*)x64 = *(const float4*)&xs[(64 << 5) + c0];
#pragma unroll
    for (int t = 0; t < 2; ++t) {
        int j = jg + t * 8;
        float sg = (j & 1) ? -1.f : 1.f;
        float2* p = T1 + (((size_t)(b * 17 + j) * 128 + xr) << 5) + c0;
        float4 v0 = make_float4((re[t][0] + x0[0] + sg * x64[0]) * s_, im[t][0] * s_,
                                (re[t][1] + x0[1] + sg * x64[1]) * s_, im[t][1] * s_);
        float4 v1 = make_float4((re[t][2] + x0[2] + sg * x64[2]) * s_, im[t][2] * s_,
                                (re[t][3] + x0[3] + sg * x64[3]) * s_, im[t][3] * s_);
        ((float4*)p)[0] = v0; ((float4*)p)[1] = v1;
    }
    if (jg == 0) {
        float re2[4] = {0,0,0,0}, im2[4] = {0,0,0,0};
        const float cs = 0.7071067811865476f, sn = -0.7071067811865476f;
        float cr2 = cs, ci2 = sn;
        for (int y = 1; y <= 63; ++y) {
            float4 s = *(const float4*)&xs[(y << 5) + c0];
            float4 d = *(const float4*)&xs[((128 - y) << 5) + c0];
            re2[0] = fmaf(s.x, cr2, re2[0]); re2[1] = fmaf(s.y, cr2, re2[1]);
            re2[2] = fmaf(s.z, cr2, re2[2]); re2[3] = fmaf(s.w, cr2, re2[3]);
            im2[0] = fmaf(d.x, ci2, im2[0]); im2[1] = fmaf(d.y, ci2, im2[1]);
            im2[2] = fmaf(d.z, ci2, im2[2]); im2[3] = fmaf(d.w, ci2, im2[3]);
            float nr = cr2 * cs - ci2 * sn;
            ci2 = fmaf(cr2, sn, ci2 * cs);
            cr2 = nr;
        }
        float2* p = T1 + (((size_t)(b * 17 + 16) * 128 + xr) << 5) + c0;
        float4 v0 = make_float4((re2[0] + x0[0] + x64[0]) * s_, im2[0] * s_,
                                (re2[1] + x0[1] + x64[1]) * s_, im2[1] * s_);
        float4 v1 = make_float4((re2[2] + x0[2] + x64[2]) * s_, im2[2] * s_,
                                (re2[3] + x0[3] + x64[3]) * s_, im2[3] * s_);
        ((float4*)p)[0] = v0; ((float4*)p)[1] = v1;
    }
}

// ---------------- K2': fused x-DFT + mix + inverse-x. block=(b,j), 512 thr.
// Stage A: conjugate-pair folded truncated x-DFT -> Xf[34][32] (LDS)
// Stage B: channel mix + t-scale -> Ys[34][32] (LDS, overlays Ts4)
// Stage C: output-pair folded inverse x-DFT -> U[b][x][j][o] (global)
__global__ __launch_bounds__(512) void k_mid_fused(
    const float2* __restrict__ T1, const float* __restrict__ w1r, const float* __restrict__ w1i,
    const float* __restrict__ w2r, const float* __restrict__ w2i,
    const float* __restrict__ tbuf, float2* __restrict__ U)
{
    int blk = blockIdx.x;
    int b = blk / 17, j = blk - b * 17;
    __shared__ float4 Ts4[2048];          // 32 KB tile; reused as Ys after stage A
    __shared__ float2 Xf[34 * 32];        // 8.5 KB
    __shared__ float ct[128], st[128];
    int tid = threadIdx.x;
    const float4* s4 = (const float4*)(T1 + (size_t)blk * 4096);
    for (int i = tid; i < 2048; i += 512) Ts4[i] = s4[i];
    if (tid < 128) {
        float a = TWO_PI_OVER_128 * (float)tid;
        sincosf(a, &st[tid], &ct[tid]);
    }
    __syncthreads();
    // fold x<->128-x: row x <- S=T[x]+T[128-x]; row 128-x <- D=T[x]-T[128-x]
    for (int i = tid; i < 1008; i += 512) {
        int x = (i >> 4) + 1, cp = i & 15;
        float4 a = Ts4[(x << 4) + cp], q = Ts4[((128 - x) << 4) + cp];
        Ts4[(x << 4) + cp] = make_float4(a.x + q.x, a.y + q.y, a.z + q.z, a.w + q.w);
        Ts4[((128 - x) << 4) + cp] = make_float4(a.x - q.x, a.y - q.y, a.z - q.z, a.w - q.w);
    }
    __syncthreads();
    // ---- stage A (threads g<16 active; g = pair unit f=g+1 -> rows f and 34-f)
    {
        int cp = tid & 15, g = tid >> 4;
        if (g < 16) {
            int f = g + 1;
            float sn, cs; sincosf(TWO_PI_OVER_128 * (float)f, &sn, &cs);
            float cr = cs, ci = sn;
            float P0=0,Q0=0,R0=0,T0=0,P1=0,Q1=0,R1=0,T1a=0;
            for (int x = 1; x <= 63; ++x) {
                float4 S = Ts4[(x << 4) + cp];
                float4 D = Ts4[((128 - x) << 4) + cp];
                P0 = fmaf(S.x, cr, P0); Q0 = fmaf(D.y, ci, Q0);
                R0 = fmaf(S.y, cr, R0); T0 = fmaf(D.x, ci, T0);
                P1 = fmaf(S.z, cr, P1); Q1 = fmaf(D.w, ci, Q1);
                R1 = fmaf(S.w, cr, R1); T1a = fmaf(D.z, ci, T1a);
                float nr = cr * cs - ci * sn;
                ci = fmaf(cr, sn, ci * cs);
                cr = nr;
            }
            float4 t0 = Ts4[cp], t64 = Ts4[(64 << 4) + cp];
            float sg = (f & 1) ? -1.f : 1.f;
            float b0r = t0.x + sg * t64.x, b0i = t0.y + sg * t64.y;
            float b1r = t0.z + sg * t64.z, b1i = t0.w + sg * t64.w;
            int ia = f, ib = 34 - f;                 // f -> ii=f ; 128-f -> ii=34-f
            Xf[ia * 32 + cp*2]   = make_float2(P0 + Q0 + b0r, R0 - T0 + b0i);
            Xf[ia * 32 + cp*2+1] = make_float2(P1 + Q1 + b1r, R1 - T1a + b1i);
            Xf[ib * 32 + cp*2]   = make_float2(P0 - Q0 + b0r, R0 + T0 + b0i);
            Xf[ib * 32 + cp*2+1] = make_float2(P1 - Q1 + b1r, R1 + T1a + b1i);
            if (g == 0) {                            // f=0 (ii=0): c=1, s=0
                float A0=0,B0=0,A1=0,B1=0;
                for (int x = 1; x <= 63; ++x) {
                    float4 S = Ts4[(x << 4) + cp];
                    A0 += S.x; B0 += S.y; A1 += S.z; B1 += S.w;
                }
                Xf[cp*2]   = make_float2(A0 + t0.x + t64.x, B0 + t0.y + t64.y);
                Xf[cp*2+1] = make_float2(A1 + t0.z + t64.z, B1 + t0.w + t64.w);
            }
            if (g == 8) {                            // f=111 single (ii=17), odd f
                float sn2, cs2; sincosf(TWO_PI_OVER_128 * 111.f, &sn2, &cs2);
                float cr2 = cs2, ci2 = sn2;
                float p0=0,q0=0,r0=0,s0=0,p1=0,q1=0,r1=0,s1=0;
                for (int x = 1; x <= 63; ++x) {
                    float4 S = Ts4[(x << 4) + cp];
                    float4 D = Ts4[((128 - x) << 4) + cp];
                    p0 = fmaf(S.x, cr2, p0); q0 = fmaf(D.y, ci2, q0);
                    r0 = fmaf(S.y, cr2, r0); s0 = fmaf(D.x, ci2, s0);
                    p1 = fmaf(S.z, cr2, p1); q1 = fmaf(D.w, ci2, q1);
                    r1 = fmaf(S.w, cr2, r1); s1 = fmaf(D.z, ci2, s1);
                    float nr = cr2 * cs2 - ci2 * sn2;
                    ci2 = fmaf(cr2, sn2, ci2 * cs2);
                    cr2 = nr;
                }
                float c0r = t0.x - t64.x, c0i = t0.y - t64.y;
                float c1r = t0.z - t64.z, c1i = t0.w - t64.w;
                Xf[17*32 + cp*2]   = make_float2(p0 + q0 + c0r, r0 - s0 + c0i);
                Xf[17*32 + cp*2+1] = make_float2(p1 + q1 + c1r, r1 - s1 + c1i);
            }
        }
    }
    __syncthreads();
    // ---- stage B: Ys[ii][o] = t * sum_c Xf[ii][c] * w[irow,j,c,o]
    float2* Ys = (float2*)Ts4;
    {
        int o = tid & 31, gi = tid >> 5;             // gi 0..15
#pragma unroll
        for (int t = 0; t < 3; ++t) {
            int ii = gi + (t << 4);
            if (ii < 34) {
                int irow = (ii < 17) ? ii : ii - 17;
                const float* wr = ((ii < 17) ? w1r : w2r) + ((irow * 17 + j) << 10) + o;
                const float* wi = ((ii < 17) ? w1i : w2i) + ((irow * 17 + j) << 10) + o;
                float ar = 0.f, ai = 0.f;
#pragma unroll 8
                for (int c = 0; c < 32; ++c) {
                    float2 xv = Xf[ii * 32 + c];
                    float wre = wr[c << 5], wim = wi[c << 5];
                    ar += xv.x * wre - xv.y * wim;
                    ai += xv.x * wim + xv.y * wre;
                }
                int which = (ii >= 17) ? 1 : 0;
                const float* tp = tbuf + ((which * 32 + b) * 17 + irow) * 2;
                float tr = tp[0], ti = tp[1];
                Ys[ii * 32 + o] = make_float2(ar * tr - ai * ti, ar * ti + ai * tr);
            }
        }
    }
    __syncthreads();
    // ---- stage C: U[x], U[128-x] pairs; x=0 and x=64 singles
    {
        int o = tid & 31, g = tid >> 5;              // g 0..15
        float yr[34], yi[34];
#pragma unroll
        for (int i = 0; i < 34; ++i) { float2 v = Ys[i * 32 + o]; yr[i] = v.x; yi[i] = v.y; }
        float2* Ub = U + ((size_t)b * 128 * 17 + j) * 32 + o;
        if (g == 0) {
            float sr = 0.f, si = 0.f;
#pragma unroll
            for (int i = 0; i < 34; ++i) { sr += yr[i]; si += yi[i]; }
            Ub[0] = make_float2(sr, si);
        }
        for (int k = 0; k < 4; ++k) {
            int x = 1 + g + (k << 4);
            if (x == 64) {
                float sr = 0.f, si = 0.f;
#pragma unroll
                for (int i = 0; i < 34; ++i) {       // (-1)^f == (-1)^ii in both ranges
                    float sg2 = (i & 1) ? -1.f : 1.f;
                    sr = fmaf(sg2, yr[i], sr); si = fmaf(sg2, yi[i], si);
                }
                Ub[(size_t)64 * 544] = make_float2(sr, si);
            } else {
                float cx = ct[x], sx = st[x];
                float A1=0,A2=0,A3=0,A4=0;
                float cr = 1.f, ci = 0.f;
#pragma unroll
                for (int i = 0; i < 17; ++i) {
                    A1 = fmaf(yr[i], cr, A1); A4 = fmaf(yr[i], ci, A4);
                    A3 = fmaf(yi[i], cr, A3); A2 = fmaf(yi[i], ci, A2);
                    float nr = cr * cx - ci * sx;
                    ci = fmaf(cr, sx, ci * cx);
                    cr = nr;
                }
                int k2 = (111 * x) & 127;
                cr = ct[k2]; ci = st[k2];
#pragma unroll
                for (int i = 17; i < 34; ++i) {
                    A1 = fmaf(yr[i], cr, A1); A4 = fmaf(yr[i], ci, A4);
                    A3 = fmaf(yi[i], cr, A3); A2 = fmaf(yi[i], ci, A2);
                    float nr = cr * cx - ci * sx;
                    ci = fmaf(cr, sx, ci * cx);
                    cr = nr;
                }
                Ub[(size_t)x * 544]         = make_float2(A1 - A2, A3 + A4);
                Ub[(size_t)(128 - x) * 544] = make_float2(A1 + A2, A3 - A4);
            }
        }
    }
}

// ---------------- Fallback K2/K3 (R3 versions, used if ws too small) ----------
__global__ __launch_bounds__(256) void k_fwd_x_mix(
    const float2* __restrict__ T1, const float* __restrict__ w1r, const float* __restrict__ w1i,
    const float* __restrict__ w2r, const float* __restrict__ w2i,
    const float* __restrict__ tbuf, float2* __restrict__ Y)
{
    int blk = blockIdx.x;
    int b = blk / 17, j = blk - b * 17;
    __shared__ float4 Ts4[2048];
    __shared__ float2 Xf[34 * 32];
    int tid = threadIdx.x;
    const float4* s4 = (const float4*)(T1 + (size_t)blk * 4096);
    for (int i = tid; i < 2048; i += 256) Ts4[i] = s4[i];
    __syncthreads();
    {
        int cp = tid & 15, g = tid >> 4;
        int il[3] = {g, g + 16, g + 32};
        float stc[3], sts[3];
#pragma unroll
        for (int t = 0; t < 3; ++t) {
            int i = il[t];
            int f = (i < 17) ? i : i + 94;
            float a = -TWO_PI_OVER_128 * (float)(f & 127);
            sincosf(a, &sts[t], &stc[t]);
        }
        float cr[3] = {1.f, 1.f, 1.f}, ci[3] = {0.f, 0.f, 0.f};
        float r0[3] = {0,0,0}, i0[3] = {0,0,0}, r1[3] = {0,0,0}, i1[3] = {0,0,0};
        const float4* Tc = Ts4 + cp;
#pragma unroll 2
        for (int xx = 0; xx < 128; ++xx) {
            float4 tv = Tc[xx << 4];
#pragma unroll
            for (int t = 0; t < 3; ++t) {
                r0[t] += tv.x * cr[t] - tv.y * ci[t];
                i0[t] += tv.x * ci[t] + tv.y * cr[t];
                r1[t] += tv.z * cr[t] - tv.w * ci[t];
                i1[t] += tv.z * ci[t] + tv.w * cr[t];
                float nr = cr[t] * stc[t] - ci[t] * sts[t];
                ci[t] = fmaf(cr[t], sts[t], ci[t] * stc[t]);
                cr[t] = nr;
            }
        }
#pragma unroll
        for (int t = 0; t < 3; ++t) {
            int i = il[t];
            if (i < 34) {
                Xf[i * 32 + cp * 2]     = make_float2(r0[t], i0[t]);
                Xf[i * 32 + cp * 2 + 1] = make_float2(r1[t], i1[t]);
            }
        }
    }
    __syncthreads();
    {
        int o = tid & 31, gi = tid >> 5;
#pragma unroll
        for (int t = 0; t < 5; ++t) {
            int ii = gi + (t << 3);
            if (ii < 34) {
                int irow = (ii < 17) ? ii : ii - 17;
                const float* wr = ((ii < 17) ? w1r : w2r) + ((irow * 17 + j) << 10) + o;
                const float* wi = ((ii < 17) ? w1i : w2i) + ((irow * 17 + j) << 10) + o;
                float ar = 0.f, ai = 0.f;
#pragma unroll 8
                for (int cc2 = 0; cc2 < 32; ++cc2) {
                    float2 xv = Xf[ii * 32 + cc2];
                    float wre = wr[cc2 << 5];
                    float wim = wi[cc2 << 5];
                    ar += xv.x * wre - xv.y * wim;
                    ai += xv.x * wim + xv.y * wre;
                }
                int which = (ii >= 17) ? 1 : 0;
                const float* tp = tbuf + ((which * 32 + b) * 17 + irow) * 2;
                float tr = tp[0], ti = tp[1];
                Y[(size_t)blk * (34 * 32) + ii * 32 + o] =
                    make_float2(ar * tr - ai * ti, ar * ti + ai * tr);
            }
        }
    }
}

__global__ __launch_bounds__(256) void k_inv_x(const float2* __restrict__ Y, float2* __restrict__ U)
{
    int blk = blockIdx.x;
    int b = blk / 17, j = blk - b * 17;
    __shared__ float2 Ys[34 * 32];
    __shared__ float ct[128], st[128];
    int tid = threadIdx.x;
    if (tid < 128) {
        float a = TWO_PI_OVER_128 * (float)tid;
        sincosf(a, &st[tid], &ct[tid]);
    }
    const float2* src = Y + (size_t)blk * (34 * 32);
    for (int i = tid; i < 34 * 32; i += 256) Ys[i] = src[i];
    __syncthreads();
    int o = tid & 31, g = tid >> 5;
    float yr[34], yi[34];
#pragma unroll
    for (int i = 0; i < 34; ++i) { float2 v = Ys[i * 32 + o]; yr[i] = v.x; yi[i] = v.y; }
    for (int xi = 0; xi < 16; ++xi) {
        int xr = (xi << 3) + g;
        float cx = ct[xr], sx = st[xr];
        float cr = 1.f, ci = 0.f, re = 0.f, im = 0.f;
#pragma unroll
        for (int i = 0; i < 17; ++i) {
            re += yr[i] * cr - yi[i] * ci;
            im += yr[i] * ci + yi[i] * cr;
            float nr = cr * cx - ci * sx;
            ci = fmaf(cr, sx, ci * cx);
            cr = nr;
        }
        int k2 = (111 * xr) & 127;
        cr = ct[k2]; ci = st[k2];
#pragma unroll
        for (int i = 17; i < 34; ++i) {
            re += yr[i] * cr - yi[i] * ci;
            im += yr[i] * ci + yi[i] * cr;
            float nr = cr * cx - ci * sx;
            ci = fmaf(cr, sx, ci * cx);
            cr = nr;
        }
        U[(((size_t)(b * 128 + xr)) * 17 + j) * 32 + o] = make_float2(re, im);
    }
}

// ---------------- K4: inverse y-axis c2r with y<->128-y pairing. block=(b,x), 128 thr.
__global__ __launch_bounds__(128) void k_inv_y(const float2* __restrict__ U, float* __restrict__ out)
{
    int blk = blockIdx.x;
    __shared__ float2 Us[17 * 32];
    int tid = threadIdx.x;
    const float4* src4 = (const float4*)(U + (size_t)blk * 544);
    float4* Us4 = (float4*)Us;
    for (int i = tid; i < 272; i += 128) Us4[i] = src4[i];
    __syncthreads();
    int cg = tid & 15, yg = tid >> 4, c0 = cg << 1;
    float base0, base1;
    {
        float4 v = *(const float4*)&Us[c0];
        base0 = v.x; base1 = v.z;
    }
    float urr[16][2], uii[16][2];
#pragma unroll
    for (int j = 1; j <= 16; ++j) {
        float4 v = *(const float4*)&Us[j * 32 + c0];
        urr[j-1][0] = 2.f * v.x; uii[j-1][0] = 2.f * v.y;
        urr[j-1][1] = 2.f * v.z; uii[j-1][1] = 2.f * v.w;
    }
    float* op = out + ((size_t)blk << 12);
    for (int k = 0; k < 9; ++k) {
        int y = yg + (k << 3);
        if (y > 64) break;
        float cy, sy; sincosf(TWO_PI_OVER_128 * (float)y, &sy, &cy);
        float cr = cy, ci = sy;
        float A0 = 0.f, A1 = 0.f, B0 = 0.f, B1 = 0.f;
#pragma unroll
        for (int j = 0; j < 16; ++j) {
            A0 = fmaf(urr[j][0], cr, A0);
            B0 = fmaf(uii[j][0], ci, B0);
            A1 = fmaf(urr[j][1], cr, A1);
            B1 = fmaf(uii[j][1], ci, B1);
            float nr = cr * cy - ci * sy;
            ci = fmaf(cr, sy, ci * cy);
            cr = nr;
        }
        *(float2*)&op[(y << 5) + c0] = make_float2(base0 + A0 - B0, base1 + A1 - B1);
        if (y > 0 && y < 64)
            *(float2*)&op[((128 - y) << 5) + c0] = make_float2(base0 + A0 + B0, base1 + A1 + B1);
    }
}

extern "C" void kernel_launch(void* const* d_in, const int* in_sizes, int n_in,
                              void* d_out, int out_size, void* d_ws, size_t ws_size,
                              hipStream_t stream)
{
    const float* x    = (const float*)d_in[0];
    const float* temb = (const float*)d_in[1];
    const float* w1r  = (const float*)d_in[2];
    const float* w1i  = (const float*)d_in[3];
    const float* w2r  = (const float*)d_in[4];
    const float* w2i  = (const float*)d_in[5];
    const float* k1r  = (const float*)d_in[6];
    const float* k1i  = (const float*)d_in[7];
    const float* k2r  = (const float*)d_in[8];
    const float* k2i  = (const float*)d_in[9];
    float* out = (float*)d_out;

    char* ws = (char*)d_ws;
    const size_t T1_BYTES = 17825792;                  // 32*17*128*32 float2
    const size_t NEED_FUSED = 2 * T1_BYTES + 8704;     // T1 + U + tbuf

    if (ws_size >= NEED_FUSED) {
        float2* T1 = (float2*)ws;
        float2* U  = (float2*)(ws + T1_BYTES);
        float*  tb = (float*)(ws + 2 * T1_BYTES);
        k_tproj    <<<32,   128, 0, stream>>>(temb, k1r, k1i, k2r, k2i, tb);
        k_fwd_y    <<<4096, 64,  0, stream>>>(x, T1);
        k_mid_fused<<<544,  512, 0, stream>>>(T1, w1r, w1i, w2r, w2i, tb, U);
        k_inv_y    <<<4096, 128, 0, stream>>>(U, out);
    } else {
        float2* T1 = (float2*)ws;
        float2* Yb = (float2*)(ws + T1_BYTES);
        float*  tb = (float*)(ws + T1_BYTES + 4734976);
        float2* U  = T1;
        k_tproj    <<<32,   128, 0, stream>>>(temb, k1r, k1i, k2r, k2i, tb);
        k_fwd_y    <<<4096, 64,  0, stream>>>(x, T1);
        k_fwd_x_mix<<<544,  256, 0, stream>>>(T1, w1r, w1i, w2r, w2i, tb, Yb);
        k_inv_x    <<<544,  256, 0, stream>>>(Yb, U);
        k_inv_y    <<<4096, 128, 0, stream>>>(U, out);
    }
}